// Round 3
// baseline (146.217 us; speedup 1.0000x reference)
//
#include <hip/hip_runtime.h>

typedef __attribute__((ext_vector_type(8))) short bf16x8;
typedef __attribute__((ext_vector_type(4))) float f32x4;

constexpr int Bsz = 32768;
constexpr int Hn  = 256;
constexpr int In  = 128;
constexpr long long BH = (long long)Bsz * Hn;

// ---------------------------------------------------------------------------
// vcell: BT=64, 8x8 thread tile, fp32, exact sequential-k fmaf order
//   (bit-identical accumulation to rounds 1-2: ks ascending by 32, kk 0..31)
// LDS: As[32][64] fp32 (8192 B) + Ws[32][256] fp32 (32768 B) = 40960 B
// ---------------------------------------------------------------------------
__device__ __forceinline__ void vcell_body(
    int vbid, char* smem,
    const float* __restrict__ v, const float* __restrict__ cur,
    const float* __restrict__ rho, const float* __restrict__ Gc,
    float* __restrict__ out)
{
    float* As = (float*)smem;            // [k][row], stride 64
    float* Ws = (float*)(smem + 8192);   // [k][col], stride 256
    const int tid = threadIdx.x;
    const int rowBase = vbid * 64;
    const int r0 = (tid >> 5) * 8;       // 8 row-groups x 8 rows
    const int c0 = (tid & 31) * 8;       // 32 col-groups x 8 cols

    float acc[8][8];
    #pragma unroll
    for (int a = 0; a < 8; ++a)
        #pragma unroll
        for (int b = 0; b < 8; ++b) acc[a][b] = 0.0f;

    const int sar = tid >> 2;            // stage-A row 0..63
    const int sak = (tid & 3) * 8;       // stage-A k offset 0,8,16,24

    for (int ks = 0; ks < Hn; ks += 32) {
        __syncthreads();
        // stage A (v): 64 rows x 32 k, transposed -> As[k][row]
        {
            const float* asrc = v + (size_t)(rowBase + sar) * Hn + ks + sak;
            float4 p0 = *(const float4*)(asrc);
            float4 p1 = *(const float4*)(asrc + 4);
            As[(sak + 0) * 64 + sar] = p0.x;
            As[(sak + 1) * 64 + sar] = p0.y;
            As[(sak + 2) * 64 + sar] = p0.z;
            As[(sak + 3) * 64 + sar] = p0.w;
            As[(sak + 4) * 64 + sar] = p1.x;
            As[(sak + 5) * 64 + sar] = p1.y;
            As[(sak + 6) * 64 + sar] = p1.z;
            As[(sak + 7) * 64 + sar] = p1.w;
        }
        // stage W (Gc): 256 rows x 32 k, transposed -> Ws[k][col], col = tid
        {
            const float* wsrc = Gc + (size_t)tid * Hn + ks;
            #pragma unroll
            for (int j = 0; j < 8; ++j) {
                float4 w4 = *(const float4*)(wsrc + j * 4);
                Ws[(j * 4 + 0) * 256 + tid] = w4.x;
                Ws[(j * 4 + 1) * 256 + tid] = w4.y;
                Ws[(j * 4 + 2) * 256 + tid] = w4.z;
                Ws[(j * 4 + 3) * 256 + tid] = w4.w;
            }
        }
        __syncthreads();
        #pragma unroll 8
        for (int kk = 0; kk < 32; ++kk) {
            float4 a0 = *(const float4*)&As[kk * 64 + r0];
            float4 a1 = *(const float4*)&As[kk * 64 + r0 + 4];
            float4 w0 = *(const float4*)&Ws[kk * 256 + c0];
            float4 w1 = *(const float4*)&Ws[kk * 256 + c0 + 4];
            float av[8] = {a0.x, a0.y, a0.z, a0.w, a1.x, a1.y, a1.z, a1.w};
            float wv[8] = {w0.x, w0.y, w0.z, w0.w, w1.x, w1.y, w1.z, w1.w};
            #pragma unroll
            for (int ii = 0; ii < 8; ++ii)
                #pragma unroll
                for (int jj = 0; jj < 8; ++jj)
                    acc[ii][jj] = fmaf(av[ii], wv[jj], acc[ii][jj]);
        }
    }

    float* out_z   = out;
    float* out_v   = out + BH;
    float* out_rho = out + 3 * BH;

    #pragma unroll
    for (int rr = 0; rr < 8; ++rr) {
        const size_t base = (size_t)(rowBase + r0 + rr) * Hn + c0;
        float4 vvA = *(const float4*)(v + base);
        float4 vvB = *(const float4*)(v + base + 4);
        float4 iiA = *(const float4*)(cur + base);
        float4 iiB = *(const float4*)(cur + base + 4);
        float4 rhA = *(const float4*)(rho + base);
        float4 rhB = *(const float4*)(rho + base + 4);
        float vv[8] = {vvA.x, vvA.y, vvA.z, vvA.w, vvB.x, vvB.y, vvB.z, vvB.w};
        float ii[8] = {iiA.x, iiA.y, iiA.z, iiA.w, iiB.x, iiB.y, iiB.z, iiB.w};
        float rh[8] = {rhA.x, rhA.y, rhA.z, rhA.w, rhB.x, rhB.y, rhB.z, rhB.w};
        float zn[8], vn[8], rn[8];
        #pragma unroll
        for (int cc = 0; cc < 8; ++cc) {
            float dv   = 0.1f * ((0.0f - vv[cc]) + ii[cc]) + acc[rr][cc];
            float vdec = vv[cc] + dv;
            float z    = (vdec - 1.0f) > 0.0f ? 1.0f : 0.0f;
            float vnew = (1.0f - z) * vdec;              // V_RESET = 0
            float mask = rh[cc] > 0.0f ? 1.0f : 0.0f;
            vnew = (1.0f - mask) * vnew + mask * vv[cc];
            z    = (1.0f - mask) * z;
            float rhon = (1.0f - z) * fmaxf(rh[cc] - mask, 0.0f) + z * 5.0f;
            zn[cc] = z; vn[cc] = vnew; rn[cc] = rhon;
        }
        *(float4*)(out_z + base)       = make_float4(zn[0], zn[1], zn[2], zn[3]);
        *(float4*)(out_z + base + 4)   = make_float4(zn[4], zn[5], zn[6], zn[7]);
        *(float4*)(out_v + base)       = make_float4(vn[0], vn[1], vn[2], vn[3]);
        *(float4*)(out_v + base + 4)   = make_float4(vn[4], vn[5], vn[6], vn[7]);
        *(float4*)(out_rho + base)     = make_float4(rn[0], rn[1], rn[2], rn[3]);
        *(float4*)(out_rho + base + 4) = make_float4(rn[4], rn[5], rn[6], rn[7]);
    }
}

// ---------------------------------------------------------------------------
// icell: i_new = 0.8*i + x@Wi^T + z@Wr^T via bf16 MFMA (unchanged from R2)
// LDS: Ab[32][64] bf16 (4096 B) + Wb[256][64] bf16 (32768 B) = 36864 B
// ---------------------------------------------------------------------------
__device__ __forceinline__ unsigned short f2bf(float f) {
    unsigned int u = __float_as_uint(f);
    unsigned int r = (u + 0x7fffu + ((u >> 16) & 1u)) >> 16;   // RNE
    return (unsigned short)r;
}
__device__ __forceinline__ bf16x8 pack8(float4 lo, float4 hi) {
    bf16x8 r;
    r[0] = (short)f2bf(lo.x); r[1] = (short)f2bf(lo.y);
    r[2] = (short)f2bf(lo.z); r[3] = (short)f2bf(lo.w);
    r[4] = (short)f2bf(hi.x); r[5] = (short)f2bf(hi.y);
    r[6] = (short)f2bf(hi.z); r[7] = (short)f2bf(hi.w);
    return r;
}

__device__ __forceinline__ void icell_body(
    int ibid, char* smem,
    const float* __restrict__ x, const float* __restrict__ z,
    const float* __restrict__ cur, const float* __restrict__ Wi,
    const float* __restrict__ Wr, float* __restrict__ out)
{
    short* Ab = (short*)smem;            // [32][64] bf16, swizzled
    short* Wb = (short*)(smem + 4096);   // [256][64] bf16, swizzled
    const int tid  = threadIdx.x;
    const int lane = tid & 63;
    const int wc   = (tid >> 6) * 64;    // wave's column base
    const int rowBase = ibid * 32;

    f32x4 acc[2][4];
    #pragma unroll
    for (int m = 0; m < 2; ++m)
        #pragma unroll
        for (int c = 0; c < 4; ++c) acc[m][c] = (f32x4){0.f, 0.f, 0.f, 0.f};

    const int ln = lane & 15, lg = lane >> 4;
    const int sar = tid >> 3;          // stage-A row (0..31)
    const int sak = (tid & 7) * 8;     // stage-A k offset (0..56)

    #pragma unroll 1
    for (int phase = 0; phase < 2; ++phase) {
        const float* A  = phase ? z : x;
        const float* W  = phase ? Wr : Wi;
        const int    K  = phase ? Hn : In;
        const int    ld = K;
        #pragma unroll 1
        for (int ks = 0; ks < K; ks += 64) {
            __syncthreads();
            {
                const float* src = A + (size_t)(rowBase + sar) * ld + ks + sak;
                float4 f0 = *(const float4*)(src);
                float4 f1 = *(const float4*)(src + 4);
                int off = (sar * 128 + sak * 2) ^ ((sar & 7) << 4);
                *(bf16x8*)((char*)Ab + off) = pack8(f0, f1);
            }
            {
                const float* wsrc = W + (size_t)tid * ld + ks;
                #pragma unroll
                for (int j = 0; j < 8; ++j) {
                    float4 f0 = *(const float4*)(wsrc + j * 8);
                    float4 f1 = *(const float4*)(wsrc + j * 8 + 4);
                    int off = (tid * 128 + j * 16) ^ ((tid & 7) << 4);
                    *(bf16x8*)((char*)Wb + off) = pack8(f0, f1);
                }
            }
            __syncthreads();
            #pragma unroll
            for (int s = 0; s < 2; ++s) {
                const int kb = s * 64 + lg * 16;
                bf16x8 a0 = *(const bf16x8*)((const char*)Ab +
                            ((ln * 128 + kb) ^ ((ln & 7) << 4)));
                bf16x8 a1 = *(const bf16x8*)((const char*)Ab +
                            (((ln + 16) * 128 + kb) ^ ((ln & 7) << 4)));
                #pragma unroll
                for (int c = 0; c < 4; ++c) {
                    const int col = wc + c * 16 + ln;
                    bf16x8 b = *(const bf16x8*)((const char*)Wb +
                               ((col * 128 + kb) ^ ((col & 7) << 4)));
                    acc[0][c] = __builtin_amdgcn_mfma_f32_16x16x32_bf16(a0, b, acc[0][c], 0, 0, 0);
                    acc[1][c] = __builtin_amdgcn_mfma_f32_16x16x32_bf16(a1, b, acc[1][c], 0, 0, 0);
                }
            }
        }
    }

    float* out_i = out + 2 * BH;
    #pragma unroll
    for (int m = 0; m < 2; ++m) {
        #pragma unroll
        for (int c = 0; c < 4; ++c) {
            const int col = wc + c * 16 + ln;
            const int rowb = rowBase + m * 16 + lg * 4;
            #pragma unroll
            for (int r = 0; r < 4; ++r) {
                const size_t idx = (size_t)(rowb + r) * Hn + col;
                out_i[idx] = 0.8f * cur[idx] + acc[m][c][r];
            }
        }
    }
}

// ---------------------------------------------------------------------------
// Fat kernel: 1536 blocks. bid%3==2 -> vcell (512 blocks, BT=64),
// else -> icell (1024 blocks, BT=32). Roles interleave so every CU hosts a
// mix of VALU-bound (vcell) and MFMA/memory-bound (icell) blocks.
// ---------------------------------------------------------------------------
__global__ __launch_bounds__(256, 4) void k_fused(
    const float* __restrict__ x, const float* __restrict__ z,
    const float* __restrict__ v, const float* __restrict__ cur,
    const float* __restrict__ rho, const float* __restrict__ Wi,
    const float* __restrict__ Wr, const float* __restrict__ Gc,
    float* __restrict__ out)
{
    __shared__ char smem[40960];
    const int bid = blockIdx.x;
    const int m3 = bid % 3;
    if (m3 == 2) {
        vcell_body(bid / 3, smem, v, cur, rho, Gc, out);
    } else {
        icell_body((bid / 3) * 2 + m3, smem, x, z, cur, Wi, Wr, out);
    }
}

extern "C" void kernel_launch(void* const* d_in, const int* in_sizes, int n_in,
                              void* d_out, int out_size, void* d_ws, size_t ws_size,
                              hipStream_t stream) {
    const float* x   = (const float*)d_in[0];
    const float* z   = (const float*)d_in[1];
    const float* v   = (const float*)d_in[2];
    const float* cur = (const float*)d_in[3];
    const float* rho = (const float*)d_in[4];
    const float* Wi  = (const float*)d_in[5];
    const float* Wr  = (const float*)d_in[6];
    const float* Gc  = (const float*)d_in[7];
    float* out = (float*)d_out;

    dim3 grid(1536), block(256);
    hipLaunchKernelGGL(k_fused, grid, block, 0, stream,
                       x, z, v, cur, rho, Wi, Wr, Gc, out);
}

// Round 4
// 132.521 us; speedup vs baseline: 1.1033x; 1.1033x over previous
//
#include <hip/hip_runtime.h>

typedef __attribute__((ext_vector_type(8))) short bf16x8;
typedef __attribute__((ext_vector_type(4))) float f32x4;

constexpr int Bsz = 32768;
constexpr int Hn  = 256;
constexpr int In  = 128;
constexpr long long BH = (long long)Bsz * Hn;
constexpr int PW = 260;   // padded LDS stride for W tile [k][col]

// ---------------------------------------------------------------------------
// vcell: BT=32, 8x4 thread tile. A (v-rows) via wave-uniform scalar loads
// (readfirstlane'd base -> s_load, SGPR operand in FMA; zero LDS traffic).
// W (Gc) staged transposed in LDS [k][col], stride 260 (conflict-padded).
// fmaf accumulation order: ks ascending by 32, kk ascending 0..31 --
// bit-identical to rounds 1-3 (z/v/rho unchanged).
// LDS: 32*260*4 = 33280 B.
// ---------------------------------------------------------------------------
__device__ __forceinline__ void vcell_body(
    int vbid, char* smem,
    const float* __restrict__ v, const float* __restrict__ cur,
    const float* __restrict__ rho, const float* __restrict__ Gc,
    float* __restrict__ out)
{
    float* Ws = (float*)smem;            // [k][col], stride 260
    const int tid = threadIdx.x;
    const int rowBase = vbid * 32;
    // wave-uniform row base -> SGPR (forces scalar loads for A)
    const int r0 = __builtin_amdgcn_readfirstlane((tid >> 6) * 8);
    const int c0 = (tid & 63) * 4;

    float acc[8][4];
    #pragma unroll
    for (int a = 0; a < 8; ++a)
        #pragma unroll
        for (int b = 0; b < 4; ++b) acc[a][b] = 0.0f;

    const float* vA = v + (size_t)(rowBase + r0) * Hn;   // uniform pointer

    for (int ks = 0; ks < Hn; ks += 32) {
        __syncthreads();
        // stage W (Gc): 256 rows x 32 k, transposed -> Ws[k][col], col = tid
        {
            const float* wsrc = Gc + (size_t)tid * Hn + ks;
            #pragma unroll
            for (int j = 0; j < 8; ++j) {
                float4 w4 = *(const float4*)(wsrc + j * 4);
                Ws[(j * 4 + 0) * PW + tid] = w4.x;
                Ws[(j * 4 + 1) * PW + tid] = w4.y;
                Ws[(j * 4 + 2) * PW + tid] = w4.z;
                Ws[(j * 4 + 3) * PW + tid] = w4.w;
            }
        }
        __syncthreads();
        // compute: 8 groups of 4 k; A-slices via uniform (scalar) loads
        #pragma unroll 2
        for (int kg = 0; kg < 8; ++kg) {
            float4 a4[8];
            #pragma unroll
            for (int rr = 0; rr < 8; ++rr)
                a4[rr] = *(const float4*)(vA + (size_t)rr * Hn + ks + kg * 4);
            #pragma unroll
            for (int kq = 0; kq < 4; ++kq) {
                const int kk = kg * 4 + kq;
                float4 w0 = *(const float4*)&Ws[kk * PW + c0];
                float wv[4] = {w0.x, w0.y, w0.z, w0.w};
                #pragma unroll
                for (int ii = 0; ii < 8; ++ii) {
                    const float av = ((const float*)&a4[ii])[kq];
                    #pragma unroll
                    for (int jj = 0; jj < 4; ++jj)
                        acc[ii][jj] = fmaf(av, wv[jj], acc[ii][jj]);
                }
            }
        }
    }

    float* out_z   = out;
    float* out_v   = out + BH;
    float* out_rho = out + 3 * BH;

    #pragma unroll
    for (int rr = 0; rr < 8; ++rr) {
        const size_t base = (size_t)(rowBase + r0 + rr) * Hn + c0;
        float4 vv4 = *(const float4*)(v + base);
        float4 ii4 = *(const float4*)(cur + base);
        float4 rh4 = *(const float4*)(rho + base);
        float vv[4] = {vv4.x, vv4.y, vv4.z, vv4.w};
        float ii[4] = {ii4.x, ii4.y, ii4.z, ii4.w};
        float rh[4] = {rh4.x, rh4.y, rh4.z, rh4.w};
        float zn[4], vn[4], rn[4];
        #pragma unroll
        for (int cc = 0; cc < 4; ++cc) {
            float dv   = 0.1f * ((0.0f - vv[cc]) + ii[cc]) + acc[rr][cc];
            float vdec = vv[cc] + dv;
            float z    = (vdec - 1.0f) > 0.0f ? 1.0f : 0.0f;
            float vnew = (1.0f - z) * vdec;              // V_RESET = 0
            float mask = rh[cc] > 0.0f ? 1.0f : 0.0f;
            vnew = (1.0f - mask) * vnew + mask * vv[cc];
            z    = (1.0f - mask) * z;
            float rhon = (1.0f - z) * fmaxf(rh[cc] - mask, 0.0f) + z * 5.0f;
            zn[cc] = z; vn[cc] = vnew; rn[cc] = rhon;
        }
        *(float4*)(out_z + base)   = make_float4(zn[0], zn[1], zn[2], zn[3]);
        *(float4*)(out_v + base)   = make_float4(vn[0], vn[1], vn[2], vn[3]);
        *(float4*)(out_rho + base) = make_float4(rn[0], rn[1], rn[2], rn[3]);
    }
}

// ---------------------------------------------------------------------------
// icell: i_new = 0.8*i + x@Wi^T + z@Wr^T via bf16 MFMA (round-2 body).
// LDS: Ab 4096 B + Wb 32768 B = 36864 B.
// ---------------------------------------------------------------------------
__device__ __forceinline__ unsigned short f2bf(float f) {
    unsigned int u = __float_as_uint(f);
    unsigned int r = (u + 0x7fffu + ((u >> 16) & 1u)) >> 16;   // RNE
    return (unsigned short)r;
}
__device__ __forceinline__ bf16x8 pack8(float4 lo, float4 hi) {
    bf16x8 r;
    r[0] = (short)f2bf(lo.x); r[1] = (short)f2bf(lo.y);
    r[2] = (short)f2bf(lo.z); r[3] = (short)f2bf(lo.w);
    r[4] = (short)f2bf(hi.x); r[5] = (short)f2bf(hi.y);
    r[6] = (short)f2bf(hi.z); r[7] = (short)f2bf(hi.w);
    return r;
}

__device__ __forceinline__ void icell_body(
    int ibid, char* smem,
    const float* __restrict__ x, const float* __restrict__ z,
    const float* __restrict__ cur, const float* __restrict__ Wi,
    const float* __restrict__ Wr, float* __restrict__ out)
{
    short* Ab = (short*)smem;            // [32][64] bf16, swizzled
    short* Wb = (short*)(smem + 4096);   // [256][64] bf16, swizzled
    const int tid  = threadIdx.x;
    const int lane = tid & 63;
    const int wc   = (tid >> 6) * 64;    // wave's column base
    const int rowBase = ibid * 32;

    f32x4 acc[2][4];
    #pragma unroll
    for (int m = 0; m < 2; ++m)
        #pragma unroll
        for (int c = 0; c < 4; ++c) acc[m][c] = (f32x4){0.f, 0.f, 0.f, 0.f};

    const int ln = lane & 15, lg = lane >> 4;
    const int sar = tid >> 3;          // stage-A row (0..31)
    const int sak = (tid & 7) * 8;     // stage-A k offset (0..56)

    #pragma unroll 1
    for (int phase = 0; phase < 2; ++phase) {
        const float* A  = phase ? z : x;
        const float* W  = phase ? Wr : Wi;
        const int    K  = phase ? Hn : In;
        const int    ld = K;
        #pragma unroll 1
        for (int ks = 0; ks < K; ks += 64) {
            __syncthreads();
            {
                const float* src = A + (size_t)(rowBase + sar) * ld + ks + sak;
                float4 f0 = *(const float4*)(src);
                float4 f1 = *(const float4*)(src + 4);
                int off = (sar * 128 + sak * 2) ^ ((sar & 7) << 4);
                *(bf16x8*)((char*)Ab + off) = pack8(f0, f1);
            }
            {
                const float* wsrc = W + (size_t)tid * ld + ks;
                #pragma unroll
                for (int j = 0; j < 8; ++j) {
                    float4 f0 = *(const float4*)(wsrc + j * 8);
                    float4 f1 = *(const float4*)(wsrc + j * 8 + 4);
                    int off = (tid * 128 + j * 16) ^ ((tid & 7) << 4);
                    *(bf16x8*)((char*)Wb + off) = pack8(f0, f1);
                }
            }
            __syncthreads();
            #pragma unroll
            for (int s = 0; s < 2; ++s) {
                const int kb = s * 64 + lg * 16;
                bf16x8 a0 = *(const bf16x8*)((const char*)Ab +
                            ((ln * 128 + kb) ^ ((ln & 7) << 4)));
                bf16x8 a1 = *(const bf16x8*)((const char*)Ab +
                            (((ln + 16) * 128 + kb) ^ ((ln & 7) << 4)));
                #pragma unroll
                for (int c = 0; c < 4; ++c) {
                    const int col = wc + c * 16 + ln;
                    bf16x8 b = *(const bf16x8*)((const char*)Wb +
                               ((col * 128 + kb) ^ ((col & 7) << 4)));
                    acc[0][c] = __builtin_amdgcn_mfma_f32_16x16x32_bf16(a0, b, acc[0][c], 0, 0, 0);
                    acc[1][c] = __builtin_amdgcn_mfma_f32_16x16x32_bf16(a1, b, acc[1][c], 0, 0, 0);
                }
            }
        }
    }

    float* out_i = out + 2 * BH;
    #pragma unroll
    for (int m = 0; m < 2; ++m) {
        #pragma unroll
        for (int c = 0; c < 4; ++c) {
            const int col = wc + c * 16 + ln;
            const int rowb = rowBase + m * 16 + lg * 4;
            #pragma unroll
            for (int r = 0; r < 4; ++r) {
                const size_t idx = (size_t)(rowb + r) * Hn + col;
                out_i[idx] = 0.8f * cur[idx] + acc[m][c][r];
            }
        }
    }
}

// ---------------------------------------------------------------------------
// Fat kernel: 2048 blocks, roles alternate so each CU/XCD hosts a mix of
// VALU-bound (vcell) and MFMA/HBM-bound (icell) blocks.
// ---------------------------------------------------------------------------
__global__ __launch_bounds__(256, 4) void k_fused(
    const float* __restrict__ x, const float* __restrict__ z,
    const float* __restrict__ v, const float* __restrict__ cur,
    const float* __restrict__ rho, const float* __restrict__ Wi,
    const float* __restrict__ Wr, const float* __restrict__ Gc,
    float* __restrict__ out)
{
    __shared__ char smem[36864];
    const int bid = blockIdx.x;
    if (bid & 1) {
        icell_body(bid >> 1, smem, x, z, cur, Wi, Wr, out);
    } else {
        vcell_body(bid >> 1, smem, v, cur, rho, Gc, out);
    }
}

extern "C" void kernel_launch(void* const* d_in, const int* in_sizes, int n_in,
                              void* d_out, int out_size, void* d_ws, size_t ws_size,
                              hipStream_t stream) {
    const float* x   = (const float*)d_in[0];
    const float* z   = (const float*)d_in[1];
    const float* v   = (const float*)d_in[2];
    const float* cur = (const float*)d_in[3];
    const float* rho = (const float*)d_in[4];
    const float* Wi  = (const float*)d_in[5];
    const float* Wr  = (const float*)d_in[6];
    const float* Gc  = (const float*)d_in[7];
    float* out = (float*)d_out;

    dim3 grid(2048), block(256);
    hipLaunchKernelGGL(k_fused, grid, block, 0, stream,
                       x, z, v, cur, rho, Wi, Wr, Gc, out);
}